// Round 13
// baseline (462.541 us; speedup 1.0000x reference)
//
#include <hip/hip_runtime.h>
#include <hip/hip_bf16.h>

typedef float  f32x4  __attribute__((ext_vector_type(4)));
typedef __bf16 bf16x4 __attribute__((ext_vector_type(4)));
typedef __bf16 bf16x8 __attribute__((ext_vector_type(8)));

#define B_SZ  64
#define NTOK  341
#define DM    768
#define NH    12
#define HD    64
#define MTOT  (B_SZ*NTOK)  // 21824
#define MP    21888
#define EQKV  2304

#define EXP2F(x) __builtin_amdgcn_exp2f(x)

__device__ __forceinline__ void gload_lds16(const __bf16* g, void* l) {
    __builtin_amdgcn_global_load_lds(
        (const __attribute__((address_space(1))) void*)g,
        (__attribute__((address_space(3))) void*)l, 16, 0, 0);
}

// ---------------- fp32 -> bf16 convert: weights only (x folded into QKV GEMM) ----------------
__global__ void cvt2_kernel(const float* __restrict__ wqf, __bf16* __restrict__ wq,
                            const float* __restrict__ wpf, __bf16* __restrict__ wp) {
    constexpr int N2 = EQKV * DM / 4;
    constexpr int N3 = DM * DM / 4;
    int i = blockIdx.x * blockDim.x + threadIdx.x;
    const int stride = gridDim.x * blockDim.x;
    for (; i < N2 + N3; i += stride) {
        const float* src; __bf16* dst; int k;
        if (i < N2) { src = wqf; dst = wq; k = i; }
        else        { src = wpf; dst = wp; k = i - N2; }
        const float4 f = ((const float4*)src)[k];
        bf16x4 v;
        v[0] = (__bf16)f.x; v[1] = (__bf16)f.y; v[2] = (__bf16)f.z; v[3] = (__bf16)f.w;
        ((bf16x4*)dst)[k] = v;
    }
}

// ---------------- 128x128xBK64 GEMM ----------------
// ACVT=1: A is fp32, reg-staged with on-the-fly bf16 convert (T14 issue-early/write-late).
// ACVT=0: A is bf16, staged via global_load_lds (proven path).
template <int EPI, int EN, int NT, int ACVT>
__global__ __launch_bounds__(256) void gemm128(
    const void* __restrict__ Araw, const __bf16* __restrict__ Bw,
    const float* __restrict__ bias,
    __bf16* __restrict__ obf, float* __restrict__ of32)
{
    __shared__ __bf16 As[2][128 * 64];
    __shared__ __bf16 Bs[2][128 * 64];

    const int tid  = threadIdx.x;
    const int lane = tid & 63;
    const int w    = tid >> 6;
    const int wm   = w >> 1, wn = w & 1;
    const int qi   = lane & 15;
    const int g    = lane >> 4;

    const int nwg = gridDim.x;
    const int bid = blockIdx.x;
    const int qq = nwg >> 3, rr = nwg & 7;
    const int xcd = bid & 7, idx = bid >> 3;
    const int wg = (xcd < rr ? xcd * (qq + 1) : rr * (qq + 1) + (xcd - rr) * qq) + idx;
    const int mtile = wg / NT;
    const int ntile = wg % NT;
    const long a_row0 = (long)mtile * 128;
    const long n0     = (long)ntile * 128;

    const int slot = lane & 7;
    const float*  aPf[4];   // ACVT=1 path (fp32 source, rows clamped in-bounds)
    const __bf16* aPb[4];   // ACVT=0 path
    const __bf16* bP[4];
#pragma unroll
    for (int it = 0; it < 4; ++it) {
        const int lrow = it * 32 + w * 8 + (lane >> 3);
        const int scol = (slot ^ (lrow & 7)) * 8;
        long arow = a_row0 + lrow;
        if (ACVT && arow > MTOT - 1) arow = MTOT - 1;   // x has exactly MTOT rows
        aPf[it] = (const float*)Araw  + arow * DM + scol;
        aPb[it] = (const __bf16*)Araw + arow * DM + scol;
        const int gcol = (lrow & 64) | ((lrow & 15) << 2) | ((lrow >> 4) & 3);
        bP[it] = Bw + (n0 + gcol) * DM + scol;
    }

    const f32x4 fzero = {0.f, 0.f, 0.f, 0.f};
    f32x4 acc[4][4];
#pragma unroll
    for (int i = 0; i < 4; ++i)
#pragma unroll
        for (int j = 0; j < 4; ++j) acc[i][j] = fzero;

    float4 anext[4][2];   // in-flight fp32 A tile (ACVT=1)

#define STAGE_B(P, K0) do { \
    _Pragma("unroll") for (int it = 0; it < 4; ++it) \
        gload_lds16(bP[it] + (K0), (char*)(&Bs[P][0]) + it * 4096 + w * 1024); \
    } while (0)

#define STAGE_A_GLD(P, K0) do { \
    _Pragma("unroll") for (int it = 0; it < 4; ++it) \
        gload_lds16(aPb[it] + (K0), (char*)(&As[P][0]) + it * 4096 + w * 1024); \
    } while (0)

#define STAGE_A_LOAD(K0) do { \
    _Pragma("unroll") for (int it = 0; it < 4; ++it) { \
        anext[it][0] = *(const float4*)(aPf[it] + (K0)); \
        anext[it][1] = *(const float4*)(aPf[it] + (K0) + 4); \
    } } while (0)

#define STAGE_A_WRITE(P) do { \
    _Pragma("unroll") for (int it = 0; it < 4; ++it) { \
        bf16x8 v_; \
        v_[0] = (__bf16)anext[it][0].x; v_[1] = (__bf16)anext[it][0].y; \
        v_[2] = (__bf16)anext[it][0].z; v_[3] = (__bf16)anext[it][0].w; \
        v_[4] = (__bf16)anext[it][1].x; v_[5] = (__bf16)anext[it][1].y; \
        v_[6] = (__bf16)anext[it][1].z; v_[7] = (__bf16)anext[it][1].w; \
        *(bf16x8*)((char*)(&As[P][0]) + it * 4096 + w * 1024 + lane * 16) = v_; \
    } } while (0)

    // prologue: tile 0
    if (ACVT) { STAGE_A_LOAD(0); STAGE_B(0, 0); STAGE_A_WRITE(0); }
    else      { STAGE_A_GLD(0, 0); STAGE_B(0, 0); }
    __syncthreads();

    int cur = 0;
    for (int k0 = 0; k0 < DM; k0 += 64) {
        const bool more = (k0 + 64 < DM);
        if (more) {
            if (ACVT) STAGE_A_LOAD(k0 + 64);   // issue early; lands during MFMA
            else      STAGE_A_GLD(cur ^ 1, k0 + 64);
            STAGE_B(cur ^ 1, k0 + 64);
        }

        const __bf16* pA = &As[cur][0];
        const __bf16* pB = &Bs[cur][0];
        bf16x8 af[4][2], bfr[4][2];
#pragma unroll
        for (int i = 0; i < 4; ++i) {
            const int fr = wm * 64 + i * 16 + qi;
#pragma unroll
            for (int ks = 0; ks < 2; ++ks)
                af[i][ks] = *(const bf16x8*)(pA + fr * 64 + (((ks << 2) + g) ^ (fr & 7)) * 8);
        }
#pragma unroll
        for (int j = 0; j < 4; ++j) {
            const int frb = wn * 64 + j * 16 + qi;
#pragma unroll
            for (int ks = 0; ks < 2; ++ks)
                bfr[j][ks] = *(const bf16x8*)(pB + frb * 64 + (((ks << 2) + g) ^ (frb & 7)) * 8);
        }
#pragma unroll
        for (int ks = 0; ks < 2; ++ks)
#pragma unroll
            for (int j = 0; j < 4; ++j)
#pragma unroll
                for (int i = 0; i < 4; ++i)
                    acc[i][j] = __builtin_amdgcn_mfma_f32_16x16x32_bf16(
                        af[i][ks], bfr[j][ks], acc[i][j], 0, 0, 0);

        if (ACVT && more) STAGE_A_WRITE(cur ^ 1);   // write late: loads landed under MFMA
        __syncthreads();
        cur ^= 1;
    }
#undef STAGE_B
#undef STAGE_A_GLD
#undef STAGE_A_LOAD
#undef STAGE_A_WRITE

    const long ge0 = n0 + wn * 64 + qi * 4;
    const float4 b4 = *(const float4*)(bias + ge0);
    const float mul = (EPI == 0 && (n0 + wn * 64) < DM) ? 0.125f * 1.44269504f : 1.f;
#pragma unroll
    for (int i = 0; i < 4; ++i) {
#pragma unroll
        for (int r = 0; r < 4; ++r) {
            const long m = a_row0 + wm * 64 + i * 16 + g * 4 + r;
            if (m < MTOT) {
                if (EPI == 0) {
                    bf16x4 pv;
                    pv[0] = (__bf16)((acc[i][0][r] + b4.x) * mul);
                    pv[1] = (__bf16)((acc[i][1][r] + b4.y) * mul);
                    pv[2] = (__bf16)((acc[i][2][r] + b4.z) * mul);
                    pv[3] = (__bf16)((acc[i][3][r] + b4.w) * mul);
                    *(bf16x4*)(obf + m * EN + ge0) = pv;
                } else {
                    float4 o;
                    o.x = acc[i][0][r] + b4.x;
                    o.y = acc[i][1][r] + b4.y;
                    o.z = acc[i][2][r] + b4.z;
                    o.w = acc[i][3][r] + b4.w;
                    *(float4*)(of32 + m * EN + ge0) = o;
                }
            }
        }
    }
}

// ---------------- attention: 3-way q-group ILP + K register prefetch ----------------
// __launch_bounds__(512,4): cap 128 VGPR -> 4 waves/SIMD (was ~140 -> 3).
__global__ __launch_bounds__(512, 4) void attn_kernel(
    const __bf16* __restrict__ qkv, __bf16* __restrict__ ao)
{
    const int h = blockIdx.x;
    const int b = blockIdx.y;
    const long rowb = (long)b * NTOK;

    __shared__ char vL[64 * 768];   // 48 KiB, V^T fragment-order, double-XOR swizzle

    const int tid  = threadIdx.x;
    const int lane = tid & 63;
    const int w    = tid >> 6;   // 0..7
    const int g    = lane >> 4;
    const int qi   = lane & 15;

    const __bf16* kbase = qkv + rowb * EQKV + DM + h * HD + g * 8;

    // ---- Q loads + first K tile issued BEFORE staging barrier
    bf16x8 qf0[3], qf1[3];
    int qg[3], limit[3];
#pragma unroll
    for (int s = 0; s < 3; ++s) {
        const int gi = w + 8 * s;
        const int q  = gi * 16 + qi;
        qg[s] = q;
        const int qrow = (q > NTOK - 1) ? (NTOK - 1) : q;
        const __bf16* qsrc = qkv + (rowb + qrow) * EQKV + h * HD + g * 8;
        qf0[s] = *(const bf16x8*)(qsrc);
        qf1[s] = *(const bf16x8*)(qsrc + 32);
        limit[s] = (q == 0) ? NTOK : (q < 5 ? 5 : (q < 21 ? 21 : (q < 85 ? 85 : NTOK)));
    }

#define LOADK(BUF, J) do { \
    const int kr0_ = 32 * (J) + qi; \
    int kr1_ = kr0_ + 16; if (kr1_ > NTOK - 1) kr1_ = NTOK - 1; \
    const __bf16* k0p_ = kbase + (long)kr0_ * EQKV; \
    const __bf16* k1p_ = kbase + (long)kr1_ * EQKV; \
    BUF[0] = *(const bf16x8*)(k0p_); \
    BUF[1] = *(const bf16x8*)(k0p_ + 32); \
    BUF[2] = *(const bf16x8*)(k1p_); \
    BUF[3] = *(const bf16x8*)(k1p_ + 32); \
} while (0)

    bf16x8 kr[2][4];
    LOADK(kr[0], 0);

    // ---- stage V
#pragma unroll
    for (int it = 0; it < 6; ++it) {
        const int c = it * 512 + tid;
        if (c < 2816) {
            const int n  = c >> 3;
            const int dc = (c & 7) << 3;
            bf16x8 e;
            if (n < NTOK) e = *(const bf16x8*)(qkv + (rowb + n) * EQKV + 1536 + h * HD + dc);
            else { e[0]=e[1]=e[2]=e[3]=e[4]=e[5]=e[6]=e[7] = (__bf16)0.f; }
            const int s   = ((n >> 5) << 2) | ((n >> 2) & 3);
            const int off = (((n >> 4) & 1) << 3) | ((n & 3) << 1);
            const int x   = c & 7;
#pragma unroll
            for (int i = 0; i < 8; ++i) {
                const int sp = s ^ i ^ x;
                *(__bf16*)(vL + (dc + i) * 768 + sp * 16 + off) = e[i];
            }
        }
    }
    __syncthreads();

    const f32x4 fzero = {0.f, 0.f, 0.f, 0.f};
    f32x4 oacc[3][4];
    float sum[3] = {0.f, 0.f, 0.f};
#pragma unroll
    for (int s = 0; s < 3; ++s)
#pragma unroll
        for (int db = 0; db < 4; ++db) oacc[s][db] = fzero;

    const int xd = (qi & 7) ^ ((qi >> 3) & 7);

#pragma unroll 2
    for (int j = 0; j < 11; ++j) {
        if (j + 1 < 11) LOADK(kr[(j + 1) & 1], j + 1);

        bf16x8 pf[3];
#pragma unroll
        for (int s = 0; s < 3; ++s) {
            f32x4 s0 = __builtin_amdgcn_mfma_f32_16x16x32_bf16(kr[j & 1][0], qf0[s], fzero, 0, 0, 0);
            s0 = __builtin_amdgcn_mfma_f32_16x16x32_bf16(kr[j & 1][1], qf1[s], s0, 0, 0, 0);
            f32x4 s1 = __builtin_amdgcn_mfma_f32_16x16x32_bf16(kr[j & 1][2], qf0[s], fzero, 0, 0, 0);
            s1 = __builtin_amdgcn_mfma_f32_16x16x32_bf16(kr[j & 1][3], qf1[s], s1, 0, 0, 0);
#pragma unroll
            for (int r = 0; r < 4; ++r) {
                const int k0i = 32 * j + g * 4 + r;
                const float p0 = (k0i < limit[s]) ? EXP2F(s0[r]) : 0.f;
                sum[s] += p0; pf[s][r] = (__bf16)p0;
                const int k1i = k0i + 16;
                const float p1 = (k1i < limit[s]) ? EXP2F(s1[r]) : 0.f;
                sum[s] += p1; pf[s][4 + r] = (__bf16)p1;
            }
        }

#pragma unroll
        for (int db = 0; db < 4; ++db) {
            const int d  = db * 16 + qi;
            const int sp = (4 * j + g) ^ xd ^ ((2 * db) & 7);
            const bf16x8 vf = *(const bf16x8*)(vL + d * 768 + sp * 16);
#pragma unroll
            for (int s = 0; s < 3; ++s)
                oacc[s][db] = __builtin_amdgcn_mfma_f32_16x16x32_bf16(
                    vf, pf[s], oacc[s][db], 0, 0, 0);
        }
    }
#undef LOADK

#pragma unroll
    for (int s = 0; s < 3; ++s) {
        float t = sum[s];
        t += __shfl_xor(t, 16);
        t += __shfl_xor(t, 32);
        const float rinv = 1.f / t;
        if (qg[s] < NTOK) {
            const long orow = (rowb + qg[s]) * DM + h * HD;
#pragma unroll
            for (int db = 0; db < 4; ++db) {
                bf16x4 pv;
#pragma unroll
                for (int r = 0; r < 4; ++r) pv[r] = (__bf16)(oacc[s][db][r] * rinv);
                *(bf16x4*)(ao + orow + db * 16 + g * 4) = pv;
            }
        }
    }
}

extern "C" void kernel_launch(void* const* d_in, const int* in_sizes, int n_in,
                              void* d_out, int out_size, void* d_ws, size_t ws_size,
                              hipStream_t stream) {
    const float* x      = (const float*)d_in[0];
    const float* qkv_w  = (const float*)d_in[1];
    const float* qkv_b  = (const float*)d_in[2];
    const float* proj_w = (const float*)d_in[3];
    const float* proj_b = (const float*)d_in[4];
    float* out = (float*)d_out;

    char* ws = (char*)d_ws;
    constexpr size_t XB_BYTES  = (size_t)MP * DM * 2;   // attn-out (ao) buffer
    constexpr size_t WQ_OFF    = XB_BYTES;
    constexpr size_t WP_OFF    = WQ_OFF + (size_t)EQKV * DM * 2;
    constexpr size_t QKV_OFF   = WP_OFF + (size_t)DM * DM * 2;

    __bf16* ao  = (__bf16*)(ws);
    __bf16* wq  = (__bf16*)(ws + WQ_OFF);
    __bf16* wp  = (__bf16*)(ws + WP_OFF);
    __bf16* qkv = (__bf16*)(ws + QKV_OFF); // [MTOT, 2304] bf16

    cvt2_kernel<<<576, 256, 0, stream>>>(qkv_w, wq, proj_w, wp);

    gemm128<0, EQKV, 18, 1><<<171 * 18, 256, 0, stream>>>(x, wq, qkv_b, qkv, nullptr);
    attn_kernel<<<dim3(NH, B_SZ), 512, 0, stream>>>(qkv, ao);
    gemm128<1, DM, 6, 0><<<171 * 6, 256, 0, stream>>>(ao, wp, proj_b, nullptr, out);
}

// Round 14
// 257.435 us; speedup vs baseline: 1.7967x; 1.7967x over previous
//
#include <hip/hip_runtime.h>
#include <hip/hip_bf16.h>

typedef float  f32x4  __attribute__((ext_vector_type(4)));
typedef __bf16 bf16x4 __attribute__((ext_vector_type(4)));
typedef __bf16 bf16x8 __attribute__((ext_vector_type(8)));

#define B_SZ  64
#define NTOK  341
#define DM    768
#define NH    12
#define HD    64
#define MTOT  (B_SZ*NTOK)  // 21824
#define MP    21888
#define EQKV  2304

#define EXP2F(x) __builtin_amdgcn_exp2f(x)

__device__ __forceinline__ void gload_lds16(const __bf16* g, void* l) {
    __builtin_amdgcn_global_load_lds(
        (const __attribute__((address_space(1))) void*)g,
        (__attribute__((address_space(3))) void*)l, 16, 0, 0);
}

// ---------------- fp32 -> bf16 convert: weights only (x folded into QKV GEMM) ----------------
__global__ void cvt2_kernel(const float* __restrict__ wqf, __bf16* __restrict__ wq,
                            const float* __restrict__ wpf, __bf16* __restrict__ wp) {
    constexpr int N2 = EQKV * DM / 4;
    constexpr int N3 = DM * DM / 4;
    int i = blockIdx.x * blockDim.x + threadIdx.x;
    const int stride = gridDim.x * blockDim.x;
    for (; i < N2 + N3; i += stride) {
        const float* src; __bf16* dst; int k;
        if (i < N2) { src = wqf; dst = wq; k = i; }
        else        { src = wpf; dst = wp; k = i - N2; }
        const float4 f = ((const float4*)src)[k];
        bf16x4 v;
        v[0] = (__bf16)f.x; v[1] = (__bf16)f.y; v[2] = (__bf16)f.z; v[3] = (__bf16)f.w;
        ((bf16x4*)dst)[k] = v;
    }
}

// ---------------- 128x128xBK64 GEMM ----------------
// ACVT=1: A is fp32, reg-staged with on-the-fly bf16 convert (T14 issue-early/write-late).
// ACVT=0: A is bf16, staged via global_load_lds (proven path).
template <int EPI, int EN, int NT, int ACVT>
__global__ __launch_bounds__(256) void gemm128(
    const void* __restrict__ Araw, const __bf16* __restrict__ Bw,
    const float* __restrict__ bias,
    __bf16* __restrict__ obf, float* __restrict__ of32)
{
    __shared__ __bf16 As[2][128 * 64];
    __shared__ __bf16 Bs[2][128 * 64];

    const int tid  = threadIdx.x;
    const int lane = tid & 63;
    const int w    = tid >> 6;
    const int wm   = w >> 1, wn = w & 1;
    const int qi   = lane & 15;
    const int g    = lane >> 4;

    const int nwg = gridDim.x;
    const int bid = blockIdx.x;
    const int qq = nwg >> 3, rr = nwg & 7;
    const int xcd = bid & 7, idx = bid >> 3;
    const int wg = (xcd < rr ? xcd * (qq + 1) : rr * (qq + 1) + (xcd - rr) * qq) + idx;
    const int mtile = wg / NT;
    const int ntile = wg % NT;
    const long a_row0 = (long)mtile * 128;
    const long n0     = (long)ntile * 128;

    const int slot = lane & 7;
    const float*  aPf[4];   // ACVT=1 path (fp32 source, rows clamped in-bounds)
    const __bf16* aPb[4];   // ACVT=0 path
    const __bf16* bP[4];
#pragma unroll
    for (int it = 0; it < 4; ++it) {
        const int lrow = it * 32 + w * 8 + (lane >> 3);
        const int scol = (slot ^ (lrow & 7)) * 8;
        long arow = a_row0 + lrow;
        if (ACVT && arow > MTOT - 1) arow = MTOT - 1;   // x has exactly MTOT rows
        aPf[it] = (const float*)Araw  + arow * DM + scol;
        aPb[it] = (const __bf16*)Araw + arow * DM + scol;
        const int gcol = (lrow & 64) | ((lrow & 15) << 2) | ((lrow >> 4) & 3);
        bP[it] = Bw + (n0 + gcol) * DM + scol;
    }

    const f32x4 fzero = {0.f, 0.f, 0.f, 0.f};
    f32x4 acc[4][4];
#pragma unroll
    for (int i = 0; i < 4; ++i)
#pragma unroll
        for (int j = 0; j < 4; ++j) acc[i][j] = fzero;

    float4 anext[4][2];   // in-flight fp32 A tile (ACVT=1)

#define STAGE_B(P, K0) do { \
    _Pragma("unroll") for (int it = 0; it < 4; ++it) \
        gload_lds16(bP[it] + (K0), (char*)(&Bs[P][0]) + it * 4096 + w * 1024); \
    } while (0)

#define STAGE_A_GLD(P, K0) do { \
    _Pragma("unroll") for (int it = 0; it < 4; ++it) \
        gload_lds16(aPb[it] + (K0), (char*)(&As[P][0]) + it * 4096 + w * 1024); \
    } while (0)

#define STAGE_A_LOAD(K0) do { \
    _Pragma("unroll") for (int it = 0; it < 4; ++it) { \
        anext[it][0] = *(const float4*)(aPf[it] + (K0)); \
        anext[it][1] = *(const float4*)(aPf[it] + (K0) + 4); \
    } } while (0)

#define STAGE_A_WRITE(P) do { \
    _Pragma("unroll") for (int it = 0; it < 4; ++it) { \
        bf16x8 v_; \
        v_[0] = (__bf16)anext[it][0].x; v_[1] = (__bf16)anext[it][0].y; \
        v_[2] = (__bf16)anext[it][0].z; v_[3] = (__bf16)anext[it][0].w; \
        v_[4] = (__bf16)anext[it][1].x; v_[5] = (__bf16)anext[it][1].y; \
        v_[6] = (__bf16)anext[it][1].z; v_[7] = (__bf16)anext[it][1].w; \
        *(bf16x8*)((char*)(&As[P][0]) + it * 4096 + w * 1024 + lane * 16) = v_; \
    } } while (0)

    // prologue: tile 0
    if (ACVT) { STAGE_A_LOAD(0); STAGE_B(0, 0); STAGE_A_WRITE(0); }
    else      { STAGE_A_GLD(0, 0); STAGE_B(0, 0); }
    __syncthreads();

    int cur = 0;
    for (int k0 = 0; k0 < DM; k0 += 64) {
        const bool more = (k0 + 64 < DM);
        if (more) {
            if (ACVT) STAGE_A_LOAD(k0 + 64);   // issue early; lands during MFMA
            else      STAGE_A_GLD(cur ^ 1, k0 + 64);
            STAGE_B(cur ^ 1, k0 + 64);
        }

        const __bf16* pA = &As[cur][0];
        const __bf16* pB = &Bs[cur][0];
        bf16x8 af[4][2], bfr[4][2];
#pragma unroll
        for (int i = 0; i < 4; ++i) {
            const int fr = wm * 64 + i * 16 + qi;
#pragma unroll
            for (int ks = 0; ks < 2; ++ks)
                af[i][ks] = *(const bf16x8*)(pA + fr * 64 + (((ks << 2) + g) ^ (fr & 7)) * 8);
        }
#pragma unroll
        for (int j = 0; j < 4; ++j) {
            const int frb = wn * 64 + j * 16 + qi;
#pragma unroll
            for (int ks = 0; ks < 2; ++ks)
                bfr[j][ks] = *(const bf16x8*)(pB + frb * 64 + (((ks << 2) + g) ^ (frb & 7)) * 8);
        }
#pragma unroll
        for (int ks = 0; ks < 2; ++ks)
#pragma unroll
            for (int j = 0; j < 4; ++j)
#pragma unroll
                for (int i = 0; i < 4; ++i)
                    acc[i][j] = __builtin_amdgcn_mfma_f32_16x16x32_bf16(
                        af[i][ks], bfr[j][ks], acc[i][j], 0, 0, 0);

        if (ACVT && more) STAGE_A_WRITE(cur ^ 1);   // write late: loads landed under MFMA
        __syncthreads();
        cur ^= 1;
    }
#undef STAGE_B
#undef STAGE_A_GLD
#undef STAGE_A_LOAD
#undef STAGE_A_WRITE

    const long ge0 = n0 + wn * 64 + qi * 4;
    const float4 b4 = *(const float4*)(bias + ge0);
    const float mul = (EPI == 0 && (n0 + wn * 64) < DM) ? 0.125f * 1.44269504f : 1.f;
#pragma unroll
    for (int i = 0; i < 4; ++i) {
#pragma unroll
        for (int r = 0; r < 4; ++r) {
            const long m = a_row0 + wm * 64 + i * 16 + g * 4 + r;
            if (m < MTOT) {
                if (EPI == 0) {
                    bf16x4 pv;
                    pv[0] = (__bf16)((acc[i][0][r] + b4.x) * mul);
                    pv[1] = (__bf16)((acc[i][1][r] + b4.y) * mul);
                    pv[2] = (__bf16)((acc[i][2][r] + b4.z) * mul);
                    pv[3] = (__bf16)((acc[i][3][r] + b4.w) * mul);
                    *(bf16x4*)(obf + m * EN + ge0) = pv;
                } else {
                    float4 o;
                    o.x = acc[i][0][r] + b4.x;
                    o.y = acc[i][1][r] + b4.y;
                    o.z = acc[i][2][r] + b4.z;
                    o.w = acc[i][3][r] + b4.w;
                    *(float4*)(of32 + m * EN + ge0) = o;
                }
            }
        }
    }
}

// ---------------- attention: 3-way q-group ILP + K register prefetch ----------------
// NO min-waves clamp: round-13's (512,4) forced VGPR=64 -> 391 MB scratch spills.
__global__ __launch_bounds__(512) void attn_kernel(
    const __bf16* __restrict__ qkv, __bf16* __restrict__ ao)
{
    const int h = blockIdx.x;
    const int b = blockIdx.y;
    const long rowb = (long)b * NTOK;

    __shared__ char vL[64 * 768];   // 48 KiB, V^T fragment-order, double-XOR swizzle

    const int tid  = threadIdx.x;
    const int lane = tid & 63;
    const int w    = tid >> 6;   // 0..7
    const int g    = lane >> 4;
    const int qi   = lane & 15;

    const __bf16* kbase = qkv + rowb * EQKV + DM + h * HD + g * 8;

    // ---- Q loads + first K tile issued BEFORE staging barrier
    bf16x8 qf0[3], qf1[3];
    int qg[3], limit[3];
#pragma unroll
    for (int s = 0; s < 3; ++s) {
        const int gi = w + 8 * s;
        const int q  = gi * 16 + qi;
        qg[s] = q;
        const int qrow = (q > NTOK - 1) ? (NTOK - 1) : q;
        const __bf16* qsrc = qkv + (rowb + qrow) * EQKV + h * HD + g * 8;
        qf0[s] = *(const bf16x8*)(qsrc);
        qf1[s] = *(const bf16x8*)(qsrc + 32);
        limit[s] = (q == 0) ? NTOK : (q < 5 ? 5 : (q < 21 ? 21 : (q < 85 ? 85 : NTOK)));
    }

#define LOADK(BUF, J) do { \
    const int kr0_ = 32 * (J) + qi; \
    int kr1_ = kr0_ + 16; if (kr1_ > NTOK - 1) kr1_ = NTOK - 1; \
    const __bf16* k0p_ = kbase + (long)kr0_ * EQKV; \
    const __bf16* k1p_ = kbase + (long)kr1_ * EQKV; \
    BUF[0] = *(const bf16x8*)(k0p_); \
    BUF[1] = *(const bf16x8*)(k0p_ + 32); \
    BUF[2] = *(const bf16x8*)(k1p_); \
    BUF[3] = *(const bf16x8*)(k1p_ + 32); \
} while (0)

    bf16x8 kr[2][4];
    LOADK(kr[0], 0);

    // ---- stage V
#pragma unroll
    for (int it = 0; it < 6; ++it) {
        const int c = it * 512 + tid;
        if (c < 2816) {
            const int n  = c >> 3;
            const int dc = (c & 7) << 3;
            bf16x8 e;
            if (n < NTOK) e = *(const bf16x8*)(qkv + (rowb + n) * EQKV + 1536 + h * HD + dc);
            else { e[0]=e[1]=e[2]=e[3]=e[4]=e[5]=e[6]=e[7] = (__bf16)0.f; }
            const int s   = ((n >> 5) << 2) | ((n >> 2) & 3);
            const int off = (((n >> 4) & 1) << 3) | ((n & 3) << 1);
            const int x   = c & 7;
#pragma unroll
            for (int i = 0; i < 8; ++i) {
                const int sp = s ^ i ^ x;
                *(__bf16*)(vL + (dc + i) * 768 + sp * 16 + off) = e[i];
            }
        }
    }
    __syncthreads();

    const f32x4 fzero = {0.f, 0.f, 0.f, 0.f};
    f32x4 oacc[3][4];
    float sum[3] = {0.f, 0.f, 0.f};
#pragma unroll
    for (int s = 0; s < 3; ++s)
#pragma unroll
        for (int db = 0; db < 4; ++db) oacc[s][db] = fzero;

    const int xd = (qi & 7) ^ ((qi >> 3) & 7);

#pragma unroll 2
    for (int j = 0; j < 11; ++j) {
        if (j + 1 < 11) LOADK(kr[(j + 1) & 1], j + 1);

        bf16x8 pf[3];
#pragma unroll
        for (int s = 0; s < 3; ++s) {
            f32x4 s0 = __builtin_amdgcn_mfma_f32_16x16x32_bf16(kr[j & 1][0], qf0[s], fzero, 0, 0, 0);
            s0 = __builtin_amdgcn_mfma_f32_16x16x32_bf16(kr[j & 1][1], qf1[s], s0, 0, 0, 0);
            f32x4 s1 = __builtin_amdgcn_mfma_f32_16x16x32_bf16(kr[j & 1][2], qf0[s], fzero, 0, 0, 0);
            s1 = __builtin_amdgcn_mfma_f32_16x16x32_bf16(kr[j & 1][3], qf1[s], s1, 0, 0, 0);
#pragma unroll
            for (int r = 0; r < 4; ++r) {
                const int k0i = 32 * j + g * 4 + r;
                const float p0 = (k0i < limit[s]) ? EXP2F(s0[r]) : 0.f;
                sum[s] += p0; pf[s][r] = (__bf16)p0;
                const int k1i = k0i + 16;
                const float p1 = (k1i < limit[s]) ? EXP2F(s1[r]) : 0.f;
                sum[s] += p1; pf[s][4 + r] = (__bf16)p1;
            }
        }

#pragma unroll
        for (int db = 0; db < 4; ++db) {
            const int d  = db * 16 + qi;
            const int sp = (4 * j + g) ^ xd ^ ((2 * db) & 7);
            const bf16x8 vf = *(const bf16x8*)(vL + d * 768 + sp * 16);
#pragma unroll
            for (int s = 0; s < 3; ++s)
                oacc[s][db] = __builtin_amdgcn_mfma_f32_16x16x32_bf16(
                    vf, pf[s], oacc[s][db], 0, 0, 0);
        }
    }
#undef LOADK

#pragma unroll
    for (int s = 0; s < 3; ++s) {
        float t = sum[s];
        t += __shfl_xor(t, 16);
        t += __shfl_xor(t, 32);
        const float rinv = 1.f / t;
        if (qg[s] < NTOK) {
            const long orow = (rowb + qg[s]) * DM + h * HD;
#pragma unroll
            for (int db = 0; db < 4; ++db) {
                bf16x4 pv;
#pragma unroll
                for (int r = 0; r < 4; ++r) pv[r] = (__bf16)(oacc[s][db][r] * rinv);
                *(bf16x4*)(ao + orow + db * 16 + g * 4) = pv;
            }
        }
    }
}

extern "C" void kernel_launch(void* const* d_in, const int* in_sizes, int n_in,
                              void* d_out, int out_size, void* d_ws, size_t ws_size,
                              hipStream_t stream) {
    const float* x      = (const float*)d_in[0];
    const float* qkv_w  = (const float*)d_in[1];
    const float* qkv_b  = (const float*)d_in[2];
    const float* proj_w = (const float*)d_in[3];
    const float* proj_b = (const float*)d_in[4];
    float* out = (float*)d_out;

    char* ws = (char*)d_ws;
    constexpr size_t XB_BYTES  = (size_t)MP * DM * 2;   // attn-out (ao) buffer
    constexpr size_t WQ_OFF    = XB_BYTES;
    constexpr size_t WP_OFF    = WQ_OFF + (size_t)EQKV * DM * 2;
    constexpr size_t QKV_OFF   = WP_OFF + (size_t)DM * DM * 2;

    __bf16* ao  = (__bf16*)(ws);
    __bf16* wq  = (__bf16*)(ws + WQ_OFF);
    __bf16* wp  = (__bf16*)(ws + WP_OFF);
    __bf16* qkv = (__bf16*)(ws + QKV_OFF); // [MTOT, 2304] bf16

    cvt2_kernel<<<576, 256, 0, stream>>>(qkv_w, wq, proj_w, wp);

    gemm128<0, EQKV, 18, 1><<<171 * 18, 256, 0, stream>>>(x, wq, qkv_b, qkv, nullptr);
    attn_kernel<<<dim3(NH, B_SZ), 512, 0, stream>>>(qkv, ao);
    gemm128<1, DM, 6, 0><<<171 * 6, 256, 0, stream>>>(ao, wp, proj_b, nullptr, out);
}

// Round 15
// 235.568 us; speedup vs baseline: 1.9635x; 1.0928x over previous
//
#include <hip/hip_runtime.h>
#include <hip/hip_bf16.h>

typedef float  f32x4  __attribute__((ext_vector_type(4)));
typedef __bf16 bf16x4 __attribute__((ext_vector_type(4)));
typedef __bf16 bf16x8 __attribute__((ext_vector_type(8)));

#define B_SZ  64
#define NTOK  341
#define DM    768
#define NH    12
#define HD    64
#define MTOT  (B_SZ*NTOK)  // 21824
#define MP    21888
#define EQKV  2304

#define EXP2F(x) __builtin_amdgcn_exp2f(x)

__device__ __forceinline__ void gload_lds16(const __bf16* g, void* l) {
    __builtin_amdgcn_global_load_lds(
        (const __attribute__((address_space(1))) void*)g,
        (__attribute__((address_space(3))) void*)l, 16, 0, 0);
}

// ---------------- fused fp32 -> bf16 convert (x, qkv_w, proj_w in one launch) ----------------
__global__ void cvt3_kernel(const float* __restrict__ x,  __bf16* __restrict__ xb,
                            const float* __restrict__ wqf, __bf16* __restrict__ wq,
                            const float* __restrict__ wpf, __bf16* __restrict__ wp) {
    constexpr int N1 = MTOT * DM / 4;
    constexpr int N2 = EQKV * DM / 4;
    constexpr int N3 = DM * DM / 4;
    int i = blockIdx.x * blockDim.x + threadIdx.x;
    const int stride = gridDim.x * blockDim.x;
    for (; i < N1 + N2 + N3; i += stride) {
        const float* src; __bf16* dst; int k;
        if (i < N1)           { src = x;   dst = xb; k = i; }
        else if (i < N1 + N2) { src = wqf; dst = wq; k = i - N1; }
        else                  { src = wpf; dst = wp; k = i - N1 - N2; }
        const float4 f = ((const float4*)src)[k];
        bf16x4 v;
        v[0] = (__bf16)f.x; v[1] = (__bf16)f.y; v[2] = (__bf16)f.z; v[3] = (__bf16)f.w;
        ((bf16x4*)dst)[k] = v;
    }
}

// ---------------- 128x128xBK32 GEMM: 32 KiB LDS -> 5 blocks/CU ----------------
// Same 2-phase dbuf + XCD-chunked grid + gamma-permuted packed epilogue as the
// proven BK=64 kernel; BK=32 halves LDS so 5 blocks interleave barrier drains.
// Swizzle: 64B rows = 4 slots; col-slot XOR with (row>>1)&3 (row-parity split
// means row&3 would leave 4-way); staging = linear LDS dest + pre-swizzled src.
template <int EPI, int EN, int NT>   // EN = output row-stride
__global__ __launch_bounds__(256) void gemm128(
    const __bf16* __restrict__ A, const __bf16* __restrict__ Bw,
    const float* __restrict__ bias,
    __bf16* __restrict__ obf, float* __restrict__ of32)
{
    __shared__ __bf16 As[2][128 * 32];   // 2 x 8 KiB
    __shared__ __bf16 Bs[2][128 * 32];   // total 32 KiB

    const int tid  = threadIdx.x;
    const int lane = tid & 63;
    const int w    = tid >> 6;
    const int wm   = w >> 1, wn = w & 1;
    const int qi   = lane & 15;
    const int g    = lane >> 4;

    const int nwg = gridDim.x;
    const int bid = blockIdx.x;
    const int qq = nwg >> 3, rr = nwg & 7;
    const int xcd = bid & 7, idx = bid >> 3;
    const int wg = (xcd < rr ? xcd * (qq + 1) : rr * (qq + 1) + (xcd - rr) * qq) + idx;
    const int mtile = wg / NT;
    const int ntile = wg % NT;
    const long a_row0 = (long)mtile * 128;
    const long n0     = (long)ntile * 128;

    // staging: 2 chunks/operand/wave; chunk = it*4 + w covers 16 rows x 64B
    const __bf16* aP[2];
    const __bf16* bP[2];
#pragma unroll
    for (int it = 0; it < 2; ++it) {
        const int lrow = (it * 4 + w) * 16 + (lane >> 2);          // 0..127
        const int scol = ((lane & 3) ^ ((lrow >> 1) & 3)) * 8;     // pre-swizzled source
        aP[it] = A + (a_row0 + lrow) * DM + scol;
        const int gcol = (lrow & 64) | ((lrow & 15) << 2) | ((lrow >> 4) & 3);
        bP[it] = Bw + (n0 + gcol) * DM + scol;
    }

    const f32x4 fzero = {0.f, 0.f, 0.f, 0.f};
    f32x4 acc[4][4];
#pragma unroll
    for (int i = 0; i < 4; ++i)
#pragma unroll
        for (int j = 0; j < 4; ++j) acc[i][j] = fzero;

#define STAGE(P, K0) do { \
    _Pragma("unroll") for (int it = 0; it < 2; ++it) { \
        gload_lds16(aP[it] + (K0), (char*)(&As[P][0]) + (it * 4 + w) * 1024); \
        gload_lds16(bP[it] + (K0), (char*)(&Bs[P][0]) + (it * 4 + w) * 1024); \
    } } while (0)

    STAGE(0, 0);
    __syncthreads();

    int cur = 0;
    for (int k0 = 0; k0 < DM; k0 += 32) {
        if (k0 + 32 < DM) STAGE(cur ^ 1, k0 + 32);   // prefetch next tile

        const __bf16* pA = &As[cur][0];
        const __bf16* pB = &Bs[cur][0];
        bf16x8 af[4], bfr[4];
#pragma unroll
        for (int i = 0; i < 4; ++i) {
            const int fr = wm * 64 + i * 16 + qi;
            af[i] = *(const bf16x8*)(pA + fr * 32 + ((g ^ ((fr >> 1) & 3)) * 8));
        }
#pragma unroll
        for (int j = 0; j < 4; ++j) {
            const int frb = wn * 64 + j * 16 + qi;
            bfr[j] = *(const bf16x8*)(pB + frb * 32 + ((g ^ ((frb >> 1) & 3)) * 8));
        }
#pragma unroll
        for (int j = 0; j < 4; ++j)
#pragma unroll
            for (int i = 0; i < 4; ++i)
                acc[i][j] = __builtin_amdgcn_mfma_f32_16x16x32_bf16(
                    af[i], bfr[j], acc[i][j], 0, 0, 0);

        __syncthreads();
        cur ^= 1;
    }
#undef STAGE

    const long ge0 = n0 + wn * 64 + qi * 4;
    const float4 b4 = *(const float4*)(bias + ge0);
    const float mul = (EPI == 0 && (n0 + wn * 64) < DM) ? 0.125f * 1.44269504f : 1.f;
#pragma unroll
    for (int i = 0; i < 4; ++i) {
#pragma unroll
        for (int r = 0; r < 4; ++r) {
            const long m = a_row0 + wm * 64 + i * 16 + g * 4 + r;
            if (m < MTOT) {
                if (EPI == 0) {
                    bf16x4 pv;
                    pv[0] = (__bf16)((acc[i][0][r] + b4.x) * mul);
                    pv[1] = (__bf16)((acc[i][1][r] + b4.y) * mul);
                    pv[2] = (__bf16)((acc[i][2][r] + b4.z) * mul);
                    pv[3] = (__bf16)((acc[i][3][r] + b4.w) * mul);
                    *(bf16x4*)(obf + m * EN + ge0) = pv;
                } else {
                    float4 o;
                    o.x = acc[i][0][r] + b4.x;
                    o.y = acc[i][1][r] + b4.y;
                    o.z = acc[i][2][r] + b4.z;
                    o.w = acc[i][3][r] + b4.w;
                    *(float4*)(of32 + m * EN + ge0) = o;
                }
            }
        }
    }
}

// ---------------- attention: 3-way q-group ILP + K register prefetch (r12 proven) ----------------
__global__ __launch_bounds__(512) void attn_kernel(
    const __bf16* __restrict__ qkv, __bf16* __restrict__ ao)
{
    const int h = blockIdx.x;
    const int b = blockIdx.y;
    const long rowb = (long)b * NTOK;

    __shared__ char vL[64 * 768];   // 48 KiB, V^T fragment-order, double-XOR swizzle

    const int tid  = threadIdx.x;
    const int lane = tid & 63;
    const int w    = tid >> 6;   // 0..7
    const int g    = lane >> 4;
    const int qi   = lane & 15;

    const __bf16* kbase = qkv + rowb * EQKV + DM + h * HD + g * 8;

    // ---- Q loads + first K tile issued BEFORE staging barrier
    bf16x8 qf0[3], qf1[3];
    int qg[3], limit[3];
#pragma unroll
    for (int s = 0; s < 3; ++s) {
        const int gi = w + 8 * s;
        const int q  = gi * 16 + qi;
        qg[s] = q;
        const int qrow = (q > NTOK - 1) ? (NTOK - 1) : q;
        const __bf16* qsrc = qkv + (rowb + qrow) * EQKV + h * HD + g * 8;
        qf0[s] = *(const bf16x8*)(qsrc);
        qf1[s] = *(const bf16x8*)(qsrc + 32);
        limit[s] = (q == 0) ? NTOK : (q < 5 ? 5 : (q < 21 ? 21 : (q < 85 ? 85 : NTOK)));
    }

#define LOADK(BUF, J) do { \
    const int kr0_ = 32 * (J) + qi; \
    int kr1_ = kr0_ + 16; if (kr1_ > NTOK - 1) kr1_ = NTOK - 1; \
    const __bf16* k0p_ = kbase + (long)kr0_ * EQKV; \
    const __bf16* k1p_ = kbase + (long)kr1_ * EQKV; \
    BUF[0] = *(const bf16x8*)(k0p_); \
    BUF[1] = *(const bf16x8*)(k0p_ + 32); \
    BUF[2] = *(const bf16x8*)(k1p_); \
    BUF[3] = *(const bf16x8*)(k1p_ + 32); \
} while (0)

    bf16x8 kr[2][4];
    LOADK(kr[0], 0);

    // ---- stage V
#pragma unroll
    for (int it = 0; it < 6; ++it) {
        const int c = it * 512 + tid;
        if (c < 2816) {
            const int n  = c >> 3;
            const int dc = (c & 7) << 3;
            bf16x8 e;
            if (n < NTOK) e = *(const bf16x8*)(qkv + (rowb + n) * EQKV + 1536 + h * HD + dc);
            else { e[0]=e[1]=e[2]=e[3]=e[4]=e[5]=e[6]=e[7] = (__bf16)0.f; }
            const int s   = ((n >> 5) << 2) | ((n >> 2) & 3);
            const int off = (((n >> 4) & 1) << 3) | ((n & 3) << 1);
            const int x   = c & 7;
#pragma unroll
            for (int i = 0; i < 8; ++i) {
                const int sp = s ^ i ^ x;
                *(__bf16*)(vL + (dc + i) * 768 + sp * 16 + off) = e[i];
            }
        }
    }
    __syncthreads();

    const f32x4 fzero = {0.f, 0.f, 0.f, 0.f};
    f32x4 oacc[3][4];
    float sum[3] = {0.f, 0.f, 0.f};
#pragma unroll
    for (int s = 0; s < 3; ++s)
#pragma unroll
        for (int db = 0; db < 4; ++db) oacc[s][db] = fzero;

    const int xd = (qi & 7) ^ ((qi >> 3) & 7);

#pragma unroll 2
    for (int j = 0; j < 11; ++j) {
        if (j + 1 < 11) LOADK(kr[(j + 1) & 1], j + 1);

        bf16x8 pf[3];
#pragma unroll
        for (int s = 0; s < 3; ++s) {
            f32x4 s0 = __builtin_amdgcn_mfma_f32_16x16x32_bf16(kr[j & 1][0], qf0[s], fzero, 0, 0, 0);
            s0 = __builtin_amdgcn_mfma_f32_16x16x32_bf16(kr[j & 1][1], qf1[s], s0, 0, 0, 0);
            f32x4 s1 = __builtin_amdgcn_mfma_f32_16x16x32_bf16(kr[j & 1][2], qf0[s], fzero, 0, 0, 0);
            s1 = __builtin_amdgcn_mfma_f32_16x16x32_bf16(kr[j & 1][3], qf1[s], s1, 0, 0, 0);
#pragma unroll
            for (int r = 0; r < 4; ++r) {
                const int k0i = 32 * j + g * 4 + r;
                const float p0 = (k0i < limit[s]) ? EXP2F(s0[r]) : 0.f;
                sum[s] += p0; pf[s][r] = (__bf16)p0;
                const int k1i = k0i + 16;
                const float p1 = (k1i < limit[s]) ? EXP2F(s1[r]) : 0.f;
                sum[s] += p1; pf[s][4 + r] = (__bf16)p1;
            }
        }

#pragma unroll
        for (int db = 0; db < 4; ++db) {
            const int d  = db * 16 + qi;
            const int sp = (4 * j + g) ^ xd ^ ((2 * db) & 7);
            const bf16x8 vf = *(const bf16x8*)(vL + d * 768 + sp * 16);
#pragma unroll
            for (int s = 0; s < 3; ++s)
                oacc[s][db] = __builtin_amdgcn_mfma_f32_16x16x32_bf16(
                    vf, pf[s], oacc[s][db], 0, 0, 0);
        }
    }
#undef LOADK

#pragma unroll
    for (int s = 0; s < 3; ++s) {
        float t = sum[s];
        t += __shfl_xor(t, 16);
        t += __shfl_xor(t, 32);
        const float rinv = 1.f / t;
        if (qg[s] < NTOK) {
            const long orow = (rowb + qg[s]) * DM + h * HD;
#pragma unroll
            for (int db = 0; db < 4; ++db) {
                bf16x4 pv;
#pragma unroll
                for (int r = 0; r < 4; ++r) pv[r] = (__bf16)(oacc[s][db][r] * rinv);
                *(bf16x4*)(ao + orow + db * 16 + g * 4) = pv;
            }
        }
    }
}

extern "C" void kernel_launch(void* const* d_in, const int* in_sizes, int n_in,
                              void* d_out, int out_size, void* d_ws, size_t ws_size,
                              hipStream_t stream) {
    const float* x      = (const float*)d_in[0];
    const float* qkv_w  = (const float*)d_in[1];
    const float* qkv_b  = (const float*)d_in[2];
    const float* proj_w = (const float*)d_in[3];
    const float* proj_b = (const float*)d_in[4];
    float* out = (float*)d_out;

    char* ws = (char*)d_ws;
    constexpr size_t XB_BYTES  = (size_t)MP * DM * 2;
    constexpr size_t WQ_OFF    = XB_BYTES;
    constexpr size_t WP_OFF    = WQ_OFF + (size_t)EQKV * DM * 2;
    constexpr size_t QKV_OFF   = WP_OFF + (size_t)DM * DM * 2;

    __bf16* xb  = (__bf16*)(ws);           // x bf16 [MP,768]; reused as attn-out
    __bf16* wq  = (__bf16*)(ws + WQ_OFF);
    __bf16* wp  = (__bf16*)(ws + WP_OFF);
    __bf16* qkv = (__bf16*)(ws + QKV_OFF); // [MTOT, 2304] bf16

    cvt3_kernel<<<2048, 256, 0, stream>>>(x, xb, qkv_w, wq, proj_w, wp);

    gemm128<0, EQKV, 18><<<171 * 18, 256, 0, stream>>>(xb, wq, qkv_b, qkv, nullptr);
    attn_kernel<<<dim3(NH, B_SZ), 512, 0, stream>>>(qkv, xb);
    gemm128<1, DM, 6><<<171 * 6, 256, 0, stream>>>(xb, wp, proj_b, nullptr, out);
}

// Round 16
// 234.075 us; speedup vs baseline: 1.9760x; 1.0064x over previous
//
#include <hip/hip_runtime.h>
#include <hip/hip_bf16.h>

typedef float  f32x4  __attribute__((ext_vector_type(4)));
typedef __bf16 bf16x4 __attribute__((ext_vector_type(4)));
typedef __bf16 bf16x8 __attribute__((ext_vector_type(8)));

#define B_SZ  64
#define NTOK  341
#define DM    768
#define NH    12
#define HD    64
#define MTOT  (B_SZ*NTOK)  // 21824
#define MP    21888
#define EQKV  2304

#define EXP2F(x) __builtin_amdgcn_exp2f(x)

__device__ __forceinline__ void gload_lds16(const __bf16* g, void* l) {
    __builtin_amdgcn_global_load_lds(
        (const __attribute__((address_space(1))) void*)g,
        (__attribute__((address_space(3))) void*)l, 16, 0, 0);
}

// ---------------- fused fp32 -> bf16 convert (x, qkv_w, proj_w in one launch) ----------------
__global__ void cvt3_kernel(const float* __restrict__ x,  __bf16* __restrict__ xb,
                            const float* __restrict__ wqf, __bf16* __restrict__ wq,
                            const float* __restrict__ wpf, __bf16* __restrict__ wp) {
    constexpr int N1 = MTOT * DM / 4;
    constexpr int N2 = EQKV * DM / 4;
    constexpr int N3 = DM * DM / 4;
    int i = blockIdx.x * blockDim.x + threadIdx.x;
    const int stride = gridDim.x * blockDim.x;
    for (; i < N1 + N2 + N3; i += stride) {
        const float* src; __bf16* dst; int k;
        if (i < N1)           { src = x;   dst = xb; k = i; }
        else if (i < N1 + N2) { src = wqf; dst = wq; k = i - N1; }
        else                  { src = wpf; dst = wp; k = i - N1 - N2; }
        const float4 f = ((const float4*)src)[k];
        bf16x4 v;
        v[0] = (__bf16)f.x; v[1] = (__bf16)f.y; v[2] = (__bf16)f.z; v[3] = (__bf16)f.w;
        ((bf16x4*)dst)[k] = v;
    }
}

// ---------------- 128x128xBK32 GEMM: TRIPLE buffer + counted vmcnt (T4 isolated) ----------------
// Per iter t: issue STAGE(t+2) [4 vmem/wave]; compute buf[t%3]; s_waitcnt vmcnt(4)
// (waits only buf[t+1]'s loads, buf[t+2] stays in flight across the barrier); raw s_barrier.
// FIFO invariant: <=8 outstanding, oldest 4 = next-needed buffer. 48 KiB LDS -> 3 blocks/CU.
template <int EPI, int EN, int NT>   // EN = output row-stride
__global__ __launch_bounds__(256) void gemm128(
    const __bf16* __restrict__ A, const __bf16* __restrict__ Bw,
    const float* __restrict__ bias,
    __bf16* __restrict__ obf, float* __restrict__ of32)
{
    __shared__ __bf16 As[3][128 * 32];   // 3 x 8 KiB
    __shared__ __bf16 Bs[3][128 * 32];   // total 48 KiB

    const int tid  = threadIdx.x;
    const int lane = tid & 63;
    const int w    = tid >> 6;
    const int wm   = w >> 1, wn = w & 1;
    const int qi   = lane & 15;
    const int g    = lane >> 4;

    const int nwg = gridDim.x;
    const int bid = blockIdx.x;
    const int qq = nwg >> 3, rr = nwg & 7;
    const int xcd = bid & 7, idx = bid >> 3;
    const int wg = (xcd < rr ? xcd * (qq + 1) : rr * (qq + 1) + (xcd - rr) * qq) + idx;
    const int mtile = wg / NT;
    const int ntile = wg % NT;
    const long a_row0 = (long)mtile * 128;
    const long n0     = (long)ntile * 128;

    // staging: 2 chunks/operand/wave; chunk = it*4 + w covers 16 rows x 64B
    const __bf16* aP[2];
    const __bf16* bP[2];
#pragma unroll
    for (int it = 0; it < 2; ++it) {
        const int lrow = (it * 4 + w) * 16 + (lane >> 2);          // 0..127
        const int scol = ((lane & 3) ^ ((lrow >> 1) & 3)) * 8;     // pre-swizzled source
        aP[it] = A + (a_row0 + lrow) * DM + scol;
        const int gcol = (lrow & 64) | ((lrow & 15) << 2) | ((lrow >> 4) & 3);
        bP[it] = Bw + (n0 + gcol) * DM + scol;
    }

    const f32x4 fzero = {0.f, 0.f, 0.f, 0.f};
    f32x4 acc[4][4];
#pragma unroll
    for (int i = 0; i < 4; ++i)
#pragma unroll
        for (int j = 0; j < 4; ++j) acc[i][j] = fzero;

#define STAGE(P, K0) do { \
    _Pragma("unroll") for (int it = 0; it < 2; ++it) { \
        gload_lds16(aP[it] + (K0), (char*)(&As[P][0]) + (it * 4 + w) * 1024); \
        gload_lds16(bP[it] + (K0), (char*)(&Bs[P][0]) + (it * 4 + w) * 1024); \
    } } while (0)

#define PIPE_SYNC(N) do { \
    asm volatile("s_waitcnt vmcnt(" #N ")" ::: "memory"); \
    __builtin_amdgcn_sched_barrier(0); \
    __builtin_amdgcn_s_barrier(); \
    __builtin_amdgcn_sched_barrier(0); \
} while (0)

    // prologue: stage tiles 0 and 1; wait tile 0 only (tile 1 stays in flight)
    STAGE(0, 0);
    STAGE(1, 32);
    PIPE_SYNC(4);

#pragma unroll 3
    for (int t = 0; t < 24; ++t) {
        if (t + 2 < 24) STAGE((t + 2) % 3, (t + 2) * 32);

        const __bf16* pA = &As[t % 3][0];
        const __bf16* pB = &Bs[t % 3][0];
        bf16x8 af[4], bfr[4];
#pragma unroll
        for (int i = 0; i < 4; ++i) {
            const int fr = wm * 64 + i * 16 + qi;
            af[i] = *(const bf16x8*)(pA + fr * 32 + ((g ^ ((fr >> 1) & 3)) * 8));
        }
#pragma unroll
        for (int j = 0; j < 4; ++j) {
            const int frb = wn * 64 + j * 16 + qi;
            bfr[j] = *(const bf16x8*)(pB + frb * 32 + ((g ^ ((frb >> 1) & 3)) * 8));
        }
#pragma unroll
        for (int j = 0; j < 4; ++j)
#pragma unroll
            for (int i = 0; i < 4; ++i)
                acc[i][j] = __builtin_amdgcn_mfma_f32_16x16x32_bf16(
                    af[i], bfr[j], acc[i][j], 0, 0, 0);

        if (t < 23) {
            if (t + 2 < 24) PIPE_SYNC(4);   // buf[t+1] done; buf[t+2] in flight
            else            PIPE_SYNC(0);   // tail: drain last staged tile
        }
    }
#undef STAGE
#undef PIPE_SYNC

    const long ge0 = n0 + wn * 64 + qi * 4;
    const float4 b4 = *(const float4*)(bias + ge0);
    const float mul = (EPI == 0 && (n0 + wn * 64) < DM) ? 0.125f * 1.44269504f : 1.f;
#pragma unroll
    for (int i = 0; i < 4; ++i) {
#pragma unroll
        for (int r = 0; r < 4; ++r) {
            const long m = a_row0 + wm * 64 + i * 16 + g * 4 + r;
            if (m < MTOT) {
                if (EPI == 0) {
                    bf16x4 pv;
                    pv[0] = (__bf16)((acc[i][0][r] + b4.x) * mul);
                    pv[1] = (__bf16)((acc[i][1][r] + b4.y) * mul);
                    pv[2] = (__bf16)((acc[i][2][r] + b4.z) * mul);
                    pv[3] = (__bf16)((acc[i][3][r] + b4.w) * mul);
                    *(bf16x4*)(obf + m * EN + ge0) = pv;
                } else {
                    float4 o;
                    o.x = acc[i][0][r] + b4.x;
                    o.y = acc[i][1][r] + b4.y;
                    o.z = acc[i][2][r] + b4.z;
                    o.w = acc[i][3][r] + b4.w;
                    *(float4*)(of32 + m * EN + ge0) = o;
                }
            }
        }
    }
}

// ---------------- attention: 3-way q-group ILP + K register prefetch (r12 proven) ----------------
__global__ __launch_bounds__(512) void attn_kernel(
    const __bf16* __restrict__ qkv, __bf16* __restrict__ ao)
{
    const int h = blockIdx.x;
    const int b = blockIdx.y;
    const long rowb = (long)b * NTOK;

    __shared__ char vL[64 * 768];   // 48 KiB, V^T fragment-order, double-XOR swizzle

    const int tid  = threadIdx.x;
    const int lane = tid & 63;
    const int w    = tid >> 6;   // 0..7
    const int g    = lane >> 4;
    const int qi   = lane & 15;

    const __bf16* kbase = qkv + rowb * EQKV + DM + h * HD + g * 8;

    // ---- Q loads + first K tile issued BEFORE staging barrier
    bf16x8 qf0[3], qf1[3];
    int qg[3], limit[3];
#pragma unroll
    for (int s = 0; s < 3; ++s) {
        const int gi = w + 8 * s;
        const int q  = gi * 16 + qi;
        qg[s] = q;
        const int qrow = (q > NTOK - 1) ? (NTOK - 1) : q;
        const __bf16* qsrc = qkv + (rowb + qrow) * EQKV + h * HD + g * 8;
        qf0[s] = *(const bf16x8*)(qsrc);
        qf1[s] = *(const bf16x8*)(qsrc + 32);
        limit[s] = (q == 0) ? NTOK : (q < 5 ? 5 : (q < 21 ? 21 : (q < 85 ? 85 : NTOK)));
    }

#define LOADK(BUF, J) do { \
    const int kr0_ = 32 * (J) + qi; \
    int kr1_ = kr0_ + 16; if (kr1_ > NTOK - 1) kr1_ = NTOK - 1; \
    const __bf16* k0p_ = kbase + (long)kr0_ * EQKV; \
    const __bf16* k1p_ = kbase + (long)kr1_ * EQKV; \
    BUF[0] = *(const bf16x8*)(k0p_); \
    BUF[1] = *(const bf16x8*)(k0p_ + 32); \
    BUF[2] = *(const bf16x8*)(k1p_); \
    BUF[3] = *(const bf16x8*)(k1p_ + 32); \
} while (0)

    bf16x8 kr[2][4];
    LOADK(kr[0], 0);

    // ---- stage V
#pragma unroll
    for (int it = 0; it < 6; ++it) {
        const int c = it * 512 + tid;
        if (c < 2816) {
            const int n  = c >> 3;
            const int dc = (c & 7) << 3;
            bf16x8 e;
            if (n < NTOK) e = *(const bf16x8*)(qkv + (rowb + n) * EQKV + 1536 + h * HD + dc);
            else { e[0]=e[1]=e[2]=e[3]=e[4]=e[5]=e[6]=e[7] = (__bf16)0.f; }
            const int s   = ((n >> 5) << 2) | ((n >> 2) & 3);
            const int off = (((n >> 4) & 1) << 3) | ((n & 3) << 1);
            const int x   = c & 7;
#pragma unroll
            for (int i = 0; i < 8; ++i) {
                const int sp = s ^ i ^ x;
                *(__bf16*)(vL + (dc + i) * 768 + sp * 16 + off) = e[i];
            }
        }
    }
    __syncthreads();

    const f32x4 fzero = {0.f, 0.f, 0.f, 0.f};
    f32x4 oacc[3][4];
    float sum[3] = {0.f, 0.f, 0.f};
#pragma unroll
    for (int s = 0; s < 3; ++s)
#pragma unroll
        for (int db = 0; db < 4; ++db) oacc[s][db] = fzero;

    const int xd = (qi & 7) ^ ((qi >> 3) & 7);

#pragma unroll 2
    for (int j = 0; j < 11; ++j) {
        if (j + 1 < 11) LOADK(kr[(j + 1) & 1], j + 1);

        bf16x8 pf[3];
#pragma unroll
        for (int s = 0; s < 3; ++s) {
            f32x4 s0 = __builtin_amdgcn_mfma_f32_16x16x32_bf16(kr[j & 1][0], qf0[s], fzero, 0, 0, 0);
            s0 = __builtin_amdgcn_mfma_f32_16x16x32_bf16(kr[j & 1][1], qf1[s], s0, 0, 0, 0);
            f32x4 s1 = __builtin_amdgcn_mfma_f32_16x16x32_bf16(kr[j & 1][2], qf0[s], fzero, 0, 0, 0);
            s1 = __builtin_amdgcn_mfma_f32_16x16x32_bf16(kr[j & 1][3], qf1[s], s1, 0, 0, 0);
#pragma unroll
            for (int r = 0; r < 4; ++r) {
                const int k0i = 32 * j + g * 4 + r;
                const float p0 = (k0i < limit[s]) ? EXP2F(s0[r]) : 0.f;
                sum[s] += p0; pf[s][r] = (__bf16)p0;
                const int k1i = k0i + 16;
                const float p1 = (k1i < limit[s]) ? EXP2F(s1[r]) : 0.f;
                sum[s] += p1; pf[s][4 + r] = (__bf16)p1;
            }
        }

#pragma unroll
        for (int db = 0; db < 4; ++db) {
            const int d  = db * 16 + qi;
            const int sp = (4 * j + g) ^ xd ^ ((2 * db) & 7);
            const bf16x8 vf = *(const bf16x8*)(vL + d * 768 + sp * 16);
#pragma unroll
            for (int s = 0; s < 3; ++s)
                oacc[s][db] = __builtin_amdgcn_mfma_f32_16x16x32_bf16(
                    vf, pf[s], oacc[s][db], 0, 0, 0);
        }
    }
#undef LOADK

#pragma unroll
    for (int s = 0; s < 3; ++s) {
        float t = sum[s];
        t += __shfl_xor(t, 16);
        t += __shfl_xor(t, 32);
        const float rinv = 1.f / t;
        if (qg[s] < NTOK) {
            const long orow = (rowb + qg[s]) * DM + h * HD;
#pragma unroll
            for (int db = 0; db < 4; ++db) {
                bf16x4 pv;
#pragma unroll
                for (int r = 0; r < 4; ++r) pv[r] = (__bf16)(oacc[s][db][r] * rinv);
                *(bf16x4*)(ao + orow + db * 16 + g * 4) = pv;
            }
        }
    }
}

extern "C" void kernel_launch(void* const* d_in, const int* in_sizes, int n_in,
                              void* d_out, int out_size, void* d_ws, size_t ws_size,
                              hipStream_t stream) {
    const float* x      = (const float*)d_in[0];
    const float* qkv_w  = (const float*)d_in[1];
    const float* qkv_b  = (const float*)d_in[2];
    const float* proj_w = (const float*)d_in[3];
    const float* proj_b = (const float*)d_in[4];
    float* out = (float*)d_out;

    char* ws = (char*)d_ws;
    constexpr size_t XB_BYTES  = (size_t)MP * DM * 2;
    constexpr size_t WQ_OFF    = XB_BYTES;
    constexpr size_t WP_OFF    = WQ_OFF + (size_t)EQKV * DM * 2;
    constexpr size_t QKV_OFF   = WP_OFF + (size_t)DM * DM * 2;

    __bf16* xb  = (__bf16*)(ws);           // x bf16 [MP,768]; reused as attn-out
    __bf16* wq  = (__bf16*)(ws + WQ_OFF);
    __bf16* wp  = (__bf16*)(ws + WP_OFF);
    __bf16* qkv = (__bf16*)(ws + QKV_OFF); // [MTOT, 2304] bf16

    cvt3_kernel<<<2048, 256, 0, stream>>>(x, xb, qkv_w, wq, proj_w, wp);

    gemm128<0, EQKV, 18><<<171 * 18, 256, 0, stream>>>(xb, wq, qkv_b, qkv, nullptr);
    attn_kernel<<<dim3(NH, B_SZ), 512, 0, stream>>>(qkv, xb);
    gemm128<1, DM, 6><<<171 * 6, 256, 0, stream>>>(xb, wp, proj_b, nullptr, out);
}

// Round 17
// 223.400 us; speedup vs baseline: 2.0705x; 1.0478x over previous
//
#include <hip/hip_runtime.h>
#include <hip/hip_bf16.h>

typedef float  f32x4  __attribute__((ext_vector_type(4)));
typedef __bf16 bf16x4 __attribute__((ext_vector_type(4)));
typedef __bf16 bf16x8 __attribute__((ext_vector_type(8)));

#define B_SZ  64
#define NTOK  341
#define DM    768
#define NH    12
#define HD    64
#define MTOT  (B_SZ*NTOK)  // 21824
#define MP    21888
#define EQKV  2304

#define EXP2F(x) __builtin_amdgcn_exp2f(x)

__device__ __forceinline__ void gload_lds16(const __bf16* g, void* l) {
    __builtin_amdgcn_global_load_lds(
        (const __attribute__((address_space(1))) void*)g,
        (__attribute__((address_space(3))) void*)l, 16, 0, 0);
}

// ---------------- fused fp32 -> bf16 convert (x, qkv_w, proj_w in one launch) ----------------
__global__ void cvt3_kernel(const float* __restrict__ x,  __bf16* __restrict__ xb,
                            const float* __restrict__ wqf, __bf16* __restrict__ wq,
                            const float* __restrict__ wpf, __bf16* __restrict__ wp) {
    constexpr int N1 = MTOT * DM / 4;
    constexpr int N2 = EQKV * DM / 4;
    constexpr int N3 = DM * DM / 4;
    int i = blockIdx.x * blockDim.x + threadIdx.x;
    const int stride = gridDim.x * blockDim.x;
    for (; i < N1 + N2 + N3; i += stride) {
        const float* src; __bf16* dst; int k;
        if (i < N1)           { src = x;   dst = xb; k = i; }
        else if (i < N1 + N2) { src = wqf; dst = wq; k = i - N1; }
        else                  { src = wpf; dst = wp; k = i - N1 - N2; }
        const float4 f = ((const float4*)src)[k];
        bf16x4 v;
        v[0] = (__bf16)f.x; v[1] = (__bf16)f.y; v[2] = (__bf16)f.z; v[3] = (__bf16)f.w;
        ((bf16x4*)dst)[k] = v;
    }
}

// ---------------- 128x128xBK64 GEMM (r12 config — frozen, best measured: 112 us QKV) ----------------
template <int EPI, int EN, int NT>   // EN = output row-stride
__global__ __launch_bounds__(256) void gemm128(
    const __bf16* __restrict__ A, const __bf16* __restrict__ Bw,
    const float* __restrict__ bias,
    __bf16* __restrict__ obf, float* __restrict__ of32)
{
    __shared__ __bf16 As[2][128 * 64];
    __shared__ __bf16 Bs[2][128 * 64];

    const int tid  = threadIdx.x;
    const int lane = tid & 63;
    const int w    = tid >> 6;
    const int wm   = w >> 1, wn = w & 1;
    const int qi   = lane & 15;
    const int g    = lane >> 4;

    const int nwg = gridDim.x;
    const int bid = blockIdx.x;
    const int qq = nwg >> 3, rr = nwg & 7;
    const int xcd = bid & 7, idx = bid >> 3;
    const int wg = (xcd < rr ? xcd * (qq + 1) : rr * (qq + 1) + (xcd - rr) * qq) + idx;
    const int mtile = wg / NT;
    const int ntile = wg % NT;
    const long a_row0 = (long)mtile * 128;
    const long n0     = (long)ntile * 128;

    const int slot = lane & 7;
    const __bf16* aP[4];
    const __bf16* bP[4];
#pragma unroll
    for (int it = 0; it < 4; ++it) {
        const int lrow = it * 32 + w * 8 + (lane >> 3);
        const int scol = (slot ^ (lrow & 7)) * 8;
        aP[it] = A + (a_row0 + lrow) * DM + scol;
        const int gcol = (lrow & 64) | ((lrow & 15) << 2) | ((lrow >> 4) & 3);
        bP[it] = Bw + (n0 + gcol) * DM + scol;
    }

    const f32x4 fzero = {0.f, 0.f, 0.f, 0.f};
    f32x4 acc[4][4];
#pragma unroll
    for (int i = 0; i < 4; ++i)
#pragma unroll
        for (int j = 0; j < 4; ++j) acc[i][j] = fzero;

#define STAGE(P, K0) do { \
    _Pragma("unroll") for (int it = 0; it < 4; ++it) { \
        gload_lds16(aP[it] + (K0), (char*)(&As[P][0]) + it * 4096 + w * 1024); \
        gload_lds16(bP[it] + (K0), (char*)(&Bs[P][0]) + it * 4096 + w * 1024); \
    } } while (0)

    STAGE(0, 0);
    __syncthreads();

    int cur = 0;
    for (int k0 = 0; k0 < DM; k0 += 64) {
        if (k0 + 64 < DM) STAGE(cur ^ 1, k0 + 64);

        const __bf16* pA = &As[cur][0];
        const __bf16* pB = &Bs[cur][0];
        bf16x8 af[4][2], bfr[4][2];
#pragma unroll
        for (int i = 0; i < 4; ++i) {
            const int fr = wm * 64 + i * 16 + qi;
#pragma unroll
            for (int ks = 0; ks < 2; ++ks)
                af[i][ks] = *(const bf16x8*)(pA + fr * 64 + (((ks << 2) + g) ^ (fr & 7)) * 8);
        }
#pragma unroll
        for (int j = 0; j < 4; ++j) {
            const int frb = wn * 64 + j * 16 + qi;
#pragma unroll
            for (int ks = 0; ks < 2; ++ks)
                bfr[j][ks] = *(const bf16x8*)(pB + frb * 64 + (((ks << 2) + g) ^ (frb & 7)) * 8);
        }
#pragma unroll
        for (int ks = 0; ks < 2; ++ks)
#pragma unroll
            for (int j = 0; j < 4; ++j)
#pragma unroll
                for (int i = 0; i < 4; ++i)
                    acc[i][j] = __builtin_amdgcn_mfma_f32_16x16x32_bf16(
                        af[i][ks], bfr[j][ks], acc[i][j], 0, 0, 0);

        __syncthreads();
        cur ^= 1;
    }
#undef STAGE

    const long ge0 = n0 + wn * 64 + qi * 4;
    const float4 b4 = *(const float4*)(bias + ge0);
    const float mul = (EPI == 0 && (n0 + wn * 64) < DM) ? 0.125f * 1.44269504f : 1.f;
#pragma unroll
    for (int i = 0; i < 4; ++i) {
#pragma unroll
        for (int r = 0; r < 4; ++r) {
            const long m = a_row0 + wm * 64 + i * 16 + g * 4 + r;
            if (m < MTOT) {
                if (EPI == 0) {
                    bf16x4 pv;
                    pv[0] = (__bf16)((acc[i][0][r] + b4.x) * mul);
                    pv[1] = (__bf16)((acc[i][1][r] + b4.y) * mul);
                    pv[2] = (__bf16)((acc[i][2][r] + b4.z) * mul);
                    pv[3] = (__bf16)((acc[i][3][r] + b4.w) * mul);
                    *(bf16x4*)(obf + m * EN + ge0) = pv;
                } else {
                    float4 o;
                    o.x = acc[i][0][r] + b4.x;
                    o.y = acc[i][1][r] + b4.y;
                    o.z = acc[i][2][r] + b4.z;
                    o.w = acc[i][3][r] + b4.w;
                    *(float4*)(of32 + m * EN + ge0) = o;
                }
            }
        }
    }
}

// ---------------- attention: 3-way q-group ILP + K prefetch + masked-tile skip + setprio ----------------
// Waves w=1..4, slot 0 (gi=1..4) have wave-uniform limit_max = 85: j-tiles 3..10 are fully
// masked (p == 0 for every lane) -> skip their QK/exp/PV entirely; output unchanged.
__global__ __launch_bounds__(512) void attn_kernel(
    const __bf16* __restrict__ qkv, __bf16* __restrict__ ao)
{
    const int h = blockIdx.x;
    const int b = blockIdx.y;
    const long rowb = (long)b * NTOK;

    __shared__ char vL[64 * 768];   // 48 KiB, V^T fragment-order, double-XOR swizzle

    const int tid  = threadIdx.x;
    const int lane = tid & 63;
    const int w    = tid >> 6;   // 0..7
    const int g    = lane >> 4;
    const int qi   = lane & 15;

    const __bf16* kbase = qkv + rowb * EQKV + DM + h * HD + g * 8;

    // ---- Q loads + first K tile issued BEFORE staging barrier
    bf16x8 qf0[3], qf1[3];
    int qg[3], limit[3];
#pragma unroll
    for (int s = 0; s < 3; ++s) {
        const int gi = w + 8 * s;
        const int q  = gi * 16 + qi;
        qg[s] = q;
        const int qrow = (q > NTOK - 1) ? (NTOK - 1) : q;
        const __bf16* qsrc = qkv + (rowb + qrow) * EQKV + h * HD + g * 8;
        qf0[s] = *(const bf16x8*)(qsrc);
        qf1[s] = *(const bf16x8*)(qsrc + 32);
        limit[s] = (q == 0) ? NTOK : (q < 5 ? 5 : (q < 21 ? 21 : (q < 85 ? 85 : NTOK)));
    }
    const bool skip0 = (w >= 1 && w <= 4);   // slot 0 = gi 1..4: all lanes masked past k=85

#define LOADK(BUF, J) do { \
    const int kr0_ = 32 * (J) + qi; \
    int kr1_ = kr0_ + 16; if (kr1_ > NTOK - 1) kr1_ = NTOK - 1; \
    const __bf16* k0p_ = kbase + (long)kr0_ * EQKV; \
    const __bf16* k1p_ = kbase + (long)kr1_ * EQKV; \
    BUF[0] = *(const bf16x8*)(k0p_); \
    BUF[1] = *(const bf16x8*)(k0p_ + 32); \
    BUF[2] = *(const bf16x8*)(k1p_); \
    BUF[3] = *(const bf16x8*)(k1p_ + 32); \
} while (0)

    bf16x8 kr[2][4];
    LOADK(kr[0], 0);

    // ---- stage V
#pragma unroll
    for (int it = 0; it < 6; ++it) {
        const int c = it * 512 + tid;
        if (c < 2816) {
            const int n  = c >> 3;
            const int dc = (c & 7) << 3;
            bf16x8 e;
            if (n < NTOK) e = *(const bf16x8*)(qkv + (rowb + n) * EQKV + 1536 + h * HD + dc);
            else { e[0]=e[1]=e[2]=e[3]=e[4]=e[5]=e[6]=e[7] = (__bf16)0.f; }
            const int s   = ((n >> 5) << 2) | ((n >> 2) & 3);
            const int off = (((n >> 4) & 1) << 3) | ((n & 3) << 1);
            const int x   = c & 7;
#pragma unroll
            for (int i = 0; i < 8; ++i) {
                const int sp = s ^ i ^ x;
                *(__bf16*)(vL + (dc + i) * 768 + sp * 16 + off) = e[i];
            }
        }
    }
    __syncthreads();

    const f32x4 fzero = {0.f, 0.f, 0.f, 0.f};
    f32x4 oacc[3][4];
    float sum[3] = {0.f, 0.f, 0.f};
#pragma unroll
    for (int s = 0; s < 3; ++s)
#pragma unroll
        for (int db = 0; db < 4; ++db) oacc[s][db] = fzero;

    const int xd = (qi & 7) ^ ((qi >> 3) & 7);

#pragma unroll 2
    for (int j = 0; j < 11; ++j) {
        if (j + 1 < 11) LOADK(kr[(j + 1) & 1], j + 1);

        const bool act0 = !(skip0 && j >= 3);   // wave-uniform

        bf16x8 pf[3];
#pragma unroll
        for (int s = 0; s < 3; ++s) {
            if (s == 0 && !act0) continue;
            __builtin_amdgcn_s_setprio(1);
            f32x4 s0 = __builtin_amdgcn_mfma_f32_16x16x32_bf16(kr[j & 1][0], qf0[s], fzero, 0, 0, 0);
            s0 = __builtin_amdgcn_mfma_f32_16x16x32_bf16(kr[j & 1][1], qf1[s], s0, 0, 0, 0);
            f32x4 s1 = __builtin_amdgcn_mfma_f32_16x16x32_bf16(kr[j & 1][2], qf0[s], fzero, 0, 0, 0);
            s1 = __builtin_amdgcn_mfma_f32_16x16x32_bf16(kr[j & 1][3], qf1[s], s1, 0, 0, 0);
            __builtin_amdgcn_s_setprio(0);
#pragma unroll
            for (int r = 0; r < 4; ++r) {
                const int k0i = 32 * j + g * 4 + r;
                const float p0 = (k0i < limit[s]) ? EXP2F(s0[r]) : 0.f;
                sum[s] += p0; pf[s][r] = (__bf16)p0;
                const int k1i = k0i + 16;
                const float p1 = (k1i < limit[s]) ? EXP2F(s1[r]) : 0.f;
                sum[s] += p1; pf[s][4 + r] = (__bf16)p1;
            }
        }

        __builtin_amdgcn_s_setprio(1);
#pragma unroll
        for (int db = 0; db < 4; ++db) {
            const int d  = db * 16 + qi;
            const int sp = (4 * j + g) ^ xd ^ ((2 * db) & 7);
            const bf16x8 vf = *(const bf16x8*)(vL + d * 768 + sp * 16);
#pragma unroll
            for (int s = 0; s < 3; ++s) {
                if (s == 0 && !act0) continue;
                oacc[s][db] = __builtin_amdgcn_mfma_f32_16x16x32_bf16(
                    vf, pf[s], oacc[s][db], 0, 0, 0);
            }
        }
        __builtin_amdgcn_s_setprio(0);
    }
#undef LOADK

#pragma unroll
    for (int s = 0; s < 3; ++s) {
        float t = sum[s];
        t += __shfl_xor(t, 16);
        t += __shfl_xor(t, 32);
        const float rinv = 1.f / t;
        if (qg[s] < NTOK) {
            const long orow = (rowb + qg[s]) * DM + h * HD;
#pragma unroll
            for (int db = 0; db < 4; ++db) {
                bf16x4 pv;
#pragma unroll
                for (int r = 0; r < 4; ++r) pv[r] = (__bf16)(oacc[s][db][r] * rinv);
                *(bf16x4*)(ao + orow + db * 16 + g * 4) = pv;
            }
        }
    }
}

extern "C" void kernel_launch(void* const* d_in, const int* in_sizes, int n_in,
                              void* d_out, int out_size, void* d_ws, size_t ws_size,
                              hipStream_t stream) {
    const float* x      = (const float*)d_in[0];
    const float* qkv_w  = (const float*)d_in[1];
    const float* qkv_b  = (const float*)d_in[2];
    const float* proj_w = (const float*)d_in[3];
    const float* proj_b = (const float*)d_in[4];
    float* out = (float*)d_out;

    char* ws = (char*)d_ws;
    constexpr size_t XB_BYTES  = (size_t)MP * DM * 2;
    constexpr size_t WQ_OFF    = XB_BYTES;
    constexpr size_t WP_OFF    = WQ_OFF + (size_t)EQKV * DM * 2;
    constexpr size_t QKV_OFF   = WP_OFF + (size_t)DM * DM * 2;

    __bf16* xb  = (__bf16*)(ws);           // x bf16 [MP,768]; reused as attn-out
    __bf16* wq  = (__bf16*)(ws + WQ_OFF);
    __bf16* wp  = (__bf16*)(ws + WP_OFF);
    __bf16* qkv = (__bf16*)(ws + QKV_OFF); // [MTOT, 2304] bf16

    cvt3_kernel<<<2048, 256, 0, stream>>>(x, xb, qkv_w, wq, proj_w, wp);

    gemm128<0, EQKV, 18><<<171 * 18, 256, 0, stream>>>(xb, wq, qkv_b, qkv, nullptr);
    attn_kernel<<<dim3(NH, B_SZ), 512, 0, stream>>>(qkv, xb);
    gemm128<1, DM, 6><<<171 * 6, 256, 0, stream>>>(xb, wp, proj_b, nullptr, out);
}